// Round 4
// baseline (1062.177 us; speedup 1.0000x reference)
//
#include <hip/hip_runtime.h>
#include <cstdint>

#define NTOK 4096
#define DDIM 1024
#define HDIM 4096
#define ODIM 1024
#define NEXP 8
#define NSLOT (2*NTOK)
#define MAXT128 72

typedef __bf16 bf16x8 __attribute__((ext_vector_type(8)));
typedef float  f32x4  __attribute__((ext_vector_type(4)));
typedef unsigned short ushort8v __attribute__((ext_vector_type(8)));

__device__ __forceinline__ unsigned short f2bf(float f) {
    union { float f; unsigned int u; } v; v.f = f;
    unsigned int r = (v.u + 0x7FFF + ((v.u >> 16) & 1)) >> 16;
    return (unsigned short)r;
}

// ---- gate: logits = relu(x@Wg), top-2 (lowest-index tie-break), fused x->bf16 cast ----
__global__ void gate_kernel(const float* __restrict__ x, const float* __restrict__ Wg,
                            int2* __restrict__ sel, float2* __restrict__ wts,
                            int* __restrict__ counts, unsigned short* __restrict__ xb) {
    int wave = threadIdx.x >> 6;
    int lane = threadIdx.x & 63;
    int n = blockIdx.x * 4 + wave;
    float acc[NEXP];
#pragma unroll
    for (int e = 0; e < NEXP; e++) acc[e] = 0.f;
    const float* xr = x + (size_t)n * DDIM;
    unsigned short* xbr = xb + (size_t)n * DDIM;
#pragma unroll
    for (int i = 0; i < 4; i++) {
        int d = i * 256 + lane * 4;
        float4 xv = *(const float4*)&xr[d];
        ushort4 o;
        o.x = f2bf(xv.x); o.y = f2bf(xv.y); o.z = f2bf(xv.z); o.w = f2bf(xv.w);
        *(ushort4*)&xbr[d] = o;
        const float* wr = Wg + (size_t)d * NEXP;
#pragma unroll
        for (int jj = 0; jj < 4; jj++) {
            float xs = (jj == 0) ? xv.x : (jj == 1) ? xv.y : (jj == 2) ? xv.z : xv.w;
#pragma unroll
            for (int e = 0; e < NEXP; e++)
                acc[e] = fmaf(xs, wr[jj * NEXP + e], acc[e]);
        }
    }
#pragma unroll
    for (int e = 0; e < NEXP; e++) {
#pragma unroll
        for (int off = 32; off >= 1; off >>= 1)
            acc[e] += __shfl_xor(acc[e], off, 64);
    }
    if (lane == 0) {
        float l0 = -1e30f, l1 = -1e30f; int e0 = 0, e1 = 0;
#pragma unroll
        for (int e = 0; e < NEXP; e++) {
            float v = fmaxf(acc[e], 0.f);     // relu before softmax
            if (v > l0)      { l1 = l0; e1 = e0; l0 = v; e0 = e; }
            else if (v > l1) { l1 = v;  e1 = e; }
        }
        float w0 = 1.f / (1.f + expf(l1 - l0));   // softmax Z cancels in top-2 renorm
        sel[n] = make_int2(e0, e1);
        wts[n] = make_float2(w0, 1.f - w0);
        atomicAdd(&counts[e0], 1);
        atomicAdd(&counts[e1], 1);
    }
}

// ---- route: scan counts -> offsets + 128-tile table, slot assignment + token->slot map ----
__global__ void route_kernel(const int2* __restrict__ sel, const float2* __restrict__ wts,
                             const int* __restrict__ counts, int* __restrict__ offsets,
                             int4* __restrict__ t128, int* __restrict__ nt128,
                             int* __restrict__ slot_token, float* __restrict__ slot_weight,
                             int2* __restrict__ tokslot) {
    __shared__ int cur[NEXP];
    int t = threadIdx.x;
    if (t == 0) {
        int s = 0, n1 = 0;
        for (int e = 0; e < NEXP; e++) {
            offsets[e] = s; cur[e] = s;
            int c = counts[e];
            for (int r = 0; r < c; r += 128)
                t128[n1++] = make_int4(e, s + r, min(128, c - r), 0);
            s += c;
        }
        offsets[NEXP] = s;
        *nt128 = n1;
    }
    __syncthreads();
    for (int n = t; n < NTOK; n += blockDim.x) {
        int2 se = sel[n]; float2 w = wts[n];
        int p0 = atomicAdd(&cur[se.x], 1);
        slot_token[p0] = n; slot_weight[p0] = w.x;
        int p1 = atomicAdd(&cur[se.y], 1);
        slot_token[p1] = n; slot_weight[p1] = w.y;
        tokslot[n] = make_int2(p0, p1);
    }
}

// ---- transpose+cast: src [R][C] fp32 -> dst [C][R] bf16, per expert (z) ----
__global__ void transpose_cast_kernel(const float* __restrict__ src, unsigned short* __restrict__ dst,
                                      int R, int C) {
    __shared__ float tile[64][65];
    int e = blockIdx.z;
    const float* s = src + (size_t)e * R * C;
    unsigned short* d = dst + (size_t)e * R * C;
    int t = threadIdx.x;                      // 256 threads
    int r0 = blockIdx.y * 64, c0 = blockIdx.x * 64;
#pragma unroll
    for (int p = 0; p < 4; p++) {
        int r = p * 16 + (t >> 4);
        int c = (t & 15) * 4;
        float4 v = *(const float4*)&s[(size_t)(r0 + r) * C + (c0 + c)];
        tile[r][c] = v.x; tile[r][c + 1] = v.y; tile[r][c + 2] = v.z; tile[r][c + 3] = v.w;
    }
    __syncthreads();
    int c = t >> 2, rb = (t & 3) * 16;
#pragma unroll
    for (int j = 0; j < 2; j++) {
        ushort8v v;
#pragma unroll
        for (int i = 0; i < 8; i++) v[i] = f2bf(tile[rb + j * 8 + i][c]);
        *(ushort8v*)&d[(size_t)(c0 + c) * R + (r0 + rb + j * 8)] = v;
    }
}

// ---- register-direct MFMA GEMM: NO LDS, NO barriers, NO staging ----
// 256 thr = 4 waves (2x2), block tile 128x128, wave tile 64x64 (FM=FN=4).
// Each MFMA fragment is one global_load_dwordx4 straight from L2 to VGPRs:
// lane(quad,lr) loads row (base+lr), elems k0+quad*8 .. +7 -- the exact operand
// layout of mfma_f32_16x16x32_bf16. Depth-1 named-set double buffer (sets 0/1),
// unroll x2; compiler inserts vmcnt waits and software-pipelines across K.
// Waves fully independent -> latency hidden by TLP (no LDS -> 3 waves/SIMD).
// SWAPPED operands mfma(bf, af): lane holds 4 consecutive OUTPUT COLUMNS ->
// packed vector epilogue stores (row = m*16+lr, cols = n*16+quad*4 .. +3).
// Grid swizzle: chunked-bijective XCD map, 8 tiles inner -> per-XCD window of
// ~8 tiles x ~12 cols keeps A rows + B panels L2-resident.
// MODE 1: A gathered via slot_token; epi: +b1, relu, bf16 uint2 -> h
// MODE 2: A = h slots; epi: +b2, relu, f32 float4 -> y (unweighted; combine later)
template <int MODE, int KDIM, int NDIM, int NCOL>
__global__ __launch_bounds__(256, 2) void moe_gemm_direct(
    const unsigned short* __restrict__ A,
    const unsigned short* __restrict__ B,
    const float* __restrict__ bias,
    const int4* __restrict__ tile_meta,
    const int* __restrict__ ntiles,
    const int* __restrict__ slot_token,
    unsigned short* __restrict__ h,
    float* __restrict__ yout) {

    constexpr int FM = 4, FN = 4;

    // ---- chunked XCD swizzle: hw id -> order o; decode (tilegroup, col, tile)
    constexpr int nwg = NCOL * MAXT128;      // % 8 == 0
    int bid = blockIdx.y * NCOL + blockIdx.x;
    int o = (bid & 7) * (nwg >> 3) + (bid >> 3);
    int tg = o / (8 * NCOL);
    int rem = o - tg * (8 * NCOL);
    int col = rem >> 3;
    int tile = tg * 8 + (rem & 7);
    if (tile >= *ntiles) return;
    int colBase = col * 128;

    int4 tm = tile_meta[tile];
    int e = tm.x, slotBase = tm.y, rows = tm.z;

    int tid = threadIdx.x;
    int w = tid >> 6, lane = tid & 63;
    int quad = lane >> 4, lr = lane & 15;
    int wm = w >> 1, wn = w & 1;             // 2x2 wave grid

    const unsigned short* Be = B + (size_t)e * NDIM * KDIM;

    // per-lane fragment row base offsets (elements); k added per step
    unsigned int aoff[FM], boff[FN];
#pragma unroll
    for (int m = 0; m < FM; m++) {
        int r = wm * 64 + m * 16 + lr;
        int slot = min(slotBase + r, NSLOT - 1);
        int arow;
        if constexpr (MODE == 1) arow = slot_token[slot];
        else                     arow = slot;
        aoff[m] = (unsigned)(arow * KDIM + quad * 8);
    }
#pragma unroll
    for (int n = 0; n < FN; n++) {
        int r = colBase + wn * 64 + n * 16 + lr;
        boff[n] = (unsigned)(r * KDIM + quad * 8);
    }

    auto ldset = [&](bf16x8 (&af)[FM], bf16x8 (&bf)[FN], int k) {
#pragma unroll
        for (int m = 0; m < FM; m++) af[m] = *(const bf16x8*)(A + aoff[m] + k);
#pragma unroll
        for (int n = 0; n < FN; n++) bf[n] = *(const bf16x8*)(Be + boff[n] + k);
    };

    f32x4 zero = {0.f, 0.f, 0.f, 0.f};
    f32x4 acc[FM][FN];
#pragma unroll
    for (int m = 0; m < FM; m++)
#pragma unroll
        for (int n = 0; n < FN; n++) acc[m][n] = zero;

    auto domfma = [&](bf16x8 (&af)[FM], bf16x8 (&bf)[FN]) {
        __builtin_amdgcn_s_setprio(1);
#pragma unroll
        for (int m = 0; m < FM; m++)
#pragma unroll
            for (int n = 0; n < FN; n++)   // SWAPPED operands -> transposed lane layout
                acc[m][n] = __builtin_amdgcn_mfma_f32_16x16x32_bf16(bf[n], af[m], acc[m][n], 0, 0, 0);
        __builtin_amdgcn_s_setprio(0);
    };

    bf16x8 a0[FM], b0[FN], a1[FM], b1[FN];
    ldset(a0, b0, 0);
    for (int k = 0; k < KDIM; k += 64) {
        ldset(a1, b1, k + 32);               // prefetch set1 while set0 computes
        domfma(a0, b0);
        if (k + 64 < KDIM) ldset(a0, b0, k + 64);  // prefetch set0 while set1 computes
        domfma(a1, b1);
    }

    // ---- epilogue (swapped layout: row = m*16+lr, cols = n*16+quad*4 .. +3)
    const float* bv = bias + e * NDIM;
    if constexpr (MODE == 1) {
#pragma unroll
        for (int m = 0; m < FM; m++) {
            int r = wm * 64 + m * 16 + lr;
            if (r < rows) {
                unsigned short* hrow = h + (size_t)(slotBase + r) * NDIM;
#pragma unroll
                for (int n = 0; n < FN; n++) {
                    int c = colBase + wn * 64 + n * 16 + quad * 4;
                    float4 bb = *(const float4*)&bv[c];
                    unsigned int lo = (unsigned)f2bf(fmaxf(acc[m][n][0] + bb.x, 0.f)) |
                                      ((unsigned)f2bf(fmaxf(acc[m][n][1] + bb.y, 0.f)) << 16);
                    unsigned int hi = (unsigned)f2bf(fmaxf(acc[m][n][2] + bb.z, 0.f)) |
                                      ((unsigned)f2bf(fmaxf(acc[m][n][3] + bb.w, 0.f)) << 16);
                    uint2 pv = make_uint2(lo, hi);
                    *(uint2*)&hrow[c] = pv;
                }
            }
        }
    } else {
#pragma unroll
        for (int m = 0; m < FM; m++) {
            int r = wm * 64 + m * 16 + lr;
            if (r < rows) {
                float* yrow = yout + (size_t)(slotBase + r) * NDIM;
#pragma unroll
                for (int n = 0; n < FN; n++) {
                    int c = colBase + wn * 64 + n * 16 + quad * 4;
                    float4 bb = *(const float4*)&bv[c];
                    float4 v;
                    v.x = fmaxf(acc[m][n][0] + bb.x, 0.f);
                    v.y = fmaxf(acc[m][n][1] + bb.y, 0.f);
                    v.z = fmaxf(acc[m][n][2] + bb.z, 0.f);
                    v.w = fmaxf(acc[m][n][3] + bb.w, 0.f);
                    *(float4*)&yrow[c] = v;
                }
            }
        }
    }
}

// ---- combine: out[n] = w0 * y[p0] + w1 * y[p1] ----
__global__ void combine_kernel(const float* __restrict__ y, const int2* __restrict__ tokslot,
                               const float2* __restrict__ wts, float* __restrict__ out) {
    int n = blockIdx.x;
    int t = threadIdx.x;
    int2 ts = tokslot[n];
    float2 w = wts[n];
    float4 a = *(const float4*)&y[(size_t)ts.x * ODIM + t * 4];
    float4 b = *(const float4*)&y[(size_t)ts.y * ODIM + t * 4];
    float4 o;
    o.x = w.x * a.x + w.y * b.x;
    o.y = w.x * a.y + w.y * b.y;
    o.z = w.x * a.z + w.y * b.z;
    o.w = w.x * a.w + w.y * b.w;
    *(float4*)&out[(size_t)n * ODIM + t * 4] = o;
}

extern "C" void kernel_launch(void* const* d_in, const int* in_sizes, int n_in,
                              void* d_out, int out_size, void* d_ws, size_t ws_size,
                              hipStream_t stream) {
    const float* x  = (const float*)d_in[0];
    const float* Wg = (const float*)d_in[1];
    const float* W1 = (const float*)d_in[2];
    const float* b1 = (const float*)d_in[3];
    const float* W2 = (const float*)d_in[4];
    const float* b2 = (const float*)d_in[5];
    float* out = (float*)d_out;

    char* ws = (char*)d_ws;
    int*    counts      = (int*)(ws + 0);
    int*    offsets     = (int*)(ws + 64);
    int*    nt128       = (int*)(ws + 128);
    int4*   t128        = (int4*)(ws + 256);
    int2*   sel         = (int2*)(ws + 4096);
    float2* wts         = (float2*)(ws + 36864);
    int*    slot_token  = (int*)(ws + 69632);
    float*  slot_weight = (float*)(ws + 102400);
    int2*   tokslot     = (int2*)(ws + 135168);
    unsigned short* xb  = (unsigned short*)(ws + 2097152);   //  8 MiB [NTOK][D]
    unsigned short* W1T = (unsigned short*)(ws + 10485760);  // 64 MiB [E][H][D]
    unsigned short* W2T = (unsigned short*)(ws + 77594624);  // 64 MiB [E][O][H]
    unsigned short* hbf = (unsigned short*)(ws + 144703488); // 64 MiB [NSLOT][H]
    float* ybf = (float*)(ws + 10485760);                    // 32 MiB [NSLOT][O], reuses dead W1T

    hipMemsetAsync(ws, 0, 256, stream);

    gate_kernel<<<NTOK / 4, 256, 0, stream>>>(x, Wg, sel, wts, counts, xb);
    route_kernel<<<1, 512, 0, stream>>>(sel, wts, counts, offsets, t128, nt128,
                                        slot_token, slot_weight, tokslot);

    transpose_cast_kernel<<<dim3(HDIM / 64, DDIM / 64, NEXP), 256, 0, stream>>>(W1, W1T, DDIM, HDIM);
    transpose_cast_kernel<<<dim3(ODIM / 64, HDIM / 64, NEXP), 256, 0, stream>>>(W2, W2T, HDIM, ODIM);

    // GEMM1: 128x128 register-direct, 32 colblocks, XCD-chunked
    moe_gemm_direct<1, DDIM, HDIM, 32><<<dim3(32, MAXT128), 256, 0, stream>>>(
        xb, W1T, b1, t128, nt128, slot_token, hbf, nullptr);
    // GEMM2: 128x128 register-direct, 8 colblocks, XCD-chunked
    moe_gemm_direct<2, HDIM, ODIM, 8><<<dim3(8, MAXT128), 256, 0, stream>>>(
        hbf, W2T, b2, t128, nt128, slot_token, nullptr, ybf);

    combine_kernel<<<NTOK, 256, 0, stream>>>(ybf, tokslot, wts, out);
}